// Round 3
// baseline (419.769 us; speedup 1.0000x reference)
//
#include <hip/hip_runtime.h>
#include <stdint.h>

typedef unsigned short u16;
typedef __attribute__((ext_vector_type(8))) short short8;
typedef __attribute__((ext_vector_type(4))) float floatx4;

constexpr int B_ = 64, P_ = 2000, D_ = 128, T_ = 200;

__device__ __forceinline__ u16 f2bf(float f) {
  union { float f; uint32_t u; } v; v.f = f;
  return (u16)((v.u + 0x7fffu + ((v.u >> 16) & 1u)) >> 16);
}

// ---- zero the stats accumulators (ws is poisoned 0xAA before every launch) ----
__global__ void k_zero(float* __restrict__ p, int n) {
  int i = blockIdx.x * 256 + threadIdx.x;
  if (i < n) p[i] = 0.f;
}

// ---- pack fp32 W1 (256x128) / W2 (128x128) into bf16 MFMA B-fragment order ----
// frag id = (ks*8 + nt)*64 + lane ; lane holds B[k0+j][nt*16 + (lane&15)], j=0..7,
// k0 = ks*32 + (lane>>4)*8.  W1: 8 ksteps (4096 frags). W2: 4 ksteps (2048 frags).
__global__ void k_prep_w(const float* __restrict__ W1, const float* __restrict__ W2,
                         u16* __restrict__ w1f, u16* __restrict__ w2f) {
  int tid = blockIdx.x * 256 + threadIdx.x;
  if (tid >= 6144) return;
  const float* W = (tid < 4096) ? W1 : W2;
  u16* dst = (tid < 4096) ? w1f : w2f;
  int fid = (tid < 4096) ? tid : tid - 4096;
  int lane = fid & 63;
  int nt = (fid >> 6) & 7;
  int ks = fid >> 9;
  int quad = lane >> 4, c = lane & 15;
  int k0 = ks * 32 + quad * 8;
#pragma unroll
  for (int j = 0; j < 8; ++j)
    dst[(size_t)fid * 8 + j] = f2bf(W[(k0 + j) * D_ + nt * 16 + c]);
}

// ---- segment sum: fp32 LDS accumulate over all P, emit bf16 tour table ----
// grid (2, 64): x = dhalf, y = batch. 4 waves; wave w takes p = w (mod 4);
// tour idx wave-uniform, lane = d (2-way bank aliasing only -> free).
__global__ __launch_bounds__(256) void k_segsum(const int* __restrict__ tidx,
                                                const float* __restrict__ emb,
                                                u16* __restrict__ tourb) {
  __shared__ float acc[T_ * 64];
  const int b = blockIdx.y;
  const int dh = blockIdx.x;
  const int tid = threadIdx.x;
  for (int i = tid; i < T_ * 64; i += 256) acc[i] = 0.f;
  __syncthreads();
  const int d = tid & 63, pr = tid >> 6;
  const float* eb = emb + ((size_t)b * 2001 + 1) * D_ + dh * 64 + d;
  const int* ti = tidx + b * P_;
  for (int p = pr; p < P_; p += 4) {
    int t = ti[p];
    atomicAdd(&acc[t * 64 + d], eb[(size_t)p * D_]);
  }
  __syncthreads();
  u16* dst = tourb + (size_t)b * T_ * D_ + dh * 64;
  for (int i = tid; i < T_ * 64; i += 256)
    dst[(size_t)(i >> 6) * D_ + (i & 63)] = f2bf(acc[i]);
}

// ---- fused MLP: h = relu(x@W1+b1); h = h@W2+b2; out[b,1+p,:] = cust + h ----
// 1000 blocks x 128 rows. 4 waves, each 32 rows (2x 16-row tiles) x 128 cols (8x 16).
// GEMMs in bf16 MFMA; residual add + store in fp32.
__global__ __launch_bounds__(256) void k_mlp(
    const int* __restrict__ tidx, const float* __restrict__ emb,
    const u16* __restrict__ tourb,
    const u16* __restrict__ w1f, const u16* __restrict__ w2f,
    const float* __restrict__ b1, const float* __restrict__ b2,
    float* __restrict__ out) {
  __shared__ u16 hbuf[128 * 136];  // stride 136: 16B-aligned rows, 2-way banks (free)
  const int tid = threadIdx.x;
  const int w = tid >> 6, lane = tid & 63, quad = lane >> 4, c = lane & 15;
  const int base = blockIdx.x * 128;
  const int r0 = w * 32;

  const float* arow[2];
  const u16* trow[2];
#pragma unroll
  for (int mt = 0; mt < 2; ++mt) {
    int m = base + r0 + mt * 16 + c;
    int b = m / P_, p = m - b * P_;
    arow[mt] = emb + ((size_t)(b * 2001 + 1 + p)) * D_;
    int t = tidx[m];
    trow[mt] = tourb + ((size_t)(b * T_ + t)) * D_;
  }
  float bias1[8], bias2[8];
#pragma unroll
  for (int nt = 0; nt < 8; ++nt) {
    bias1[nt] = b1[nt * 16 + c];
    bias2[nt] = b2[nt * 16 + c];
  }

  // ---- GEMM1: K=256 (cust fp32->bf16 k 0..127, tour bf16 k 128..255) ----
  floatx4 acc[2][8];
#pragma unroll
  for (int mt = 0; mt < 2; ++mt)
#pragma unroll
    for (int nt = 0; nt < 8; ++nt) acc[mt][nt] = (floatx4)0.f;

#pragma unroll
  for (int ks = 0; ks < 8; ++ks) {
    short8 a[2];
#pragma unroll
    for (int mt = 0; mt < 2; ++mt) {
      if (ks < 4) {
        const float* src = arow[mt] + ks * 32 + quad * 8;
        floatx4 x0 = *(const floatx4*)src;
        floatx4 x1 = *(const floatx4*)(src + 4);
#pragma unroll
        for (int j = 0; j < 4; ++j) {
          a[mt][j]     = (short)f2bf(x0[j]);
          a[mt][4 + j] = (short)f2bf(x1[j]);
        }
      } else {
        a[mt] = *(const short8*)(trow[mt] + (ks - 4) * 32 + quad * 8);
      }
    }
#pragma unroll
    for (int nt = 0; nt < 8; ++nt) {
      short8 bf = *(const short8*)(w1f + ((size_t)((ks * 8 + nt) * 64 + lane)) * 8);
      acc[0][nt] = __builtin_amdgcn_mfma_f32_16x16x32_bf16(a[0], bf, acc[0][nt], 0, 0, 0);
      acc[1][nt] = __builtin_amdgcn_mfma_f32_16x16x32_bf16(a[1], bf, acc[1][nt], 0, 0, 0);
    }
  }

  // epilogue 1: relu(acc + b1) -> hbuf bf16 (C layout: row = quad*4+r, col = lane&15)
#pragma unroll
  for (int mt = 0; mt < 2; ++mt)
#pragma unroll
    for (int nt = 0; nt < 8; ++nt)
#pragma unroll
      for (int r = 0; r < 4; ++r) {
        int row = r0 + mt * 16 + quad * 4 + r;
        float v = acc[mt][nt][r] + bias1[nt];
        hbuf[row * 136 + nt * 16 + c] = f2bf(v > 0.f ? v : 0.f);
      }
  __syncthreads();

  // ---- GEMM2: K=128, A-frags from hbuf ----
  floatx4 acc2[2][8];
#pragma unroll
  for (int mt = 0; mt < 2; ++mt)
#pragma unroll
    for (int nt = 0; nt < 8; ++nt) acc2[mt][nt] = (floatx4)0.f;

#pragma unroll
  for (int ks = 0; ks < 4; ++ks) {
    short8 a[2];
#pragma unroll
    for (int mt = 0; mt < 2; ++mt)
      a[mt] = *(const short8*)(&hbuf[(r0 + mt * 16 + c) * 136 + ks * 32 + quad * 8]);
#pragma unroll
    for (int nt = 0; nt < 8; ++nt) {
      short8 bf = *(const short8*)(w2f + ((size_t)((ks * 8 + nt) * 64 + lane)) * 8);
      acc2[0][nt] = __builtin_amdgcn_mfma_f32_16x16x32_bf16(a[0], bf, acc2[0][nt], 0, 0, 0);
      acc2[1][nt] = __builtin_amdgcn_mfma_f32_16x16x32_bf16(a[1], bf, acc2[1][nt], 0, 0, 0);
    }
  }

  // epilogue 2: out[b,1+p,col] = cust(fp32) + (acc2 + b2); C-layout stores:
  // lanes c=0..15 of a quad write 16 consecutive fp32 = 64B segments (efficient).
#pragma unroll
  for (int mt = 0; mt < 2; ++mt)
#pragma unroll
    for (int nt = 0; nt < 8; ++nt)
#pragma unroll
      for (int r = 0; r < 4; ++r) {
        int row = r0 + mt * 16 + quad * 4 + r;
        int m = base + row;
        int b = m / P_, p = m - b * P_;
        size_t gaddr = ((size_t)(b * 2001 + 1 + p)) * D_ + nt * 16 + c;
        out[gaddr] = emb[gaddr] + (acc2[mt][nt][r] + bias2[nt]);
      }
}

// ---- per-(b,d) sum / sumsq over the P rows of `out`. grid (8, 64) ----
__global__ __launch_bounds__(256) void k_stats(const float* __restrict__ out,
                                               float* __restrict__ ssum,
                                               float* __restrict__ ssq) {
  const int b = blockIdx.y, ps = blockIdx.x;
  const int tid = threadIdx.x;
  const int col = tid & 127, rh = tid >> 7;
  float s = 0.f, s2 = 0.f;
  const float* src = out + ((size_t)b * 2001 + 1) * D_ + col;
  for (int p = ps * 250 + rh; p < ps * 250 + 250; p += 2) {
    float v = src[(size_t)p * D_];
    s += v; s2 += v * v;
  }
  __shared__ float ls[128], ls2[128];
  if (rh == 0) { ls[col] = s; ls2[col] = s2; }
  __syncthreads();
  if (rh == 1) { ls[col] += s; ls2[col] += s2; }
  __syncthreads();
  if (rh == 0) {
    atomicAdd(&ssum[b * D_ + col], ls[col]);
    atomicAdd(&ssq[b * D_ + col], ls2[col]);
  }
}

// ---- finalize: scale = rstd*gamma, shift = beta - mean*scale ----
__global__ void k_final(const float* __restrict__ ssum, const float* __restrict__ ssq,
                        const float* __restrict__ gamma, const float* __restrict__ beta,
                        float* __restrict__ scale, float* __restrict__ shift) {
  int i = blockIdx.x * 256 + threadIdx.x;
  if (i >= B_ * D_) return;
  int col = i & 127;
  float mean = ssum[i] * (1.f / P_);
  float var = ssq[i] * (1.f / P_) - mean * mean;
  float rstd = rsqrtf(var + 1e-5f);
  float sc = rstd * gamma[col];
  scale[i] = sc;
  shift[i] = beta[col] - mean * sc;
}

// ---- in-place normalize + depot-row copy. 8004 blocks * 256 thr * 8 elems exact ----
__global__ __launch_bounds__(256) void k_out(
    const float* __restrict__ emb,
    const float* __restrict__ scale, const float* __restrict__ shift,
    float* __restrict__ out) {
  size_t i = ((size_t)blockIdx.x * 256 + threadIdx.x) * 8;
  int row = (int)(i >> 7), col = (int)(i & 127);
  int b = row / 2001, r = row - b * 2001;
  if (r == 0) {
    *(floatx4*)(out + i)     = *(const floatx4*)(emb + i);
    *(floatx4*)(out + i + 4) = *(const floatx4*)(emb + i + 4);
  } else {
    floatx4 a0 = *(const floatx4*)(out + i);
    floatx4 a1 = *(const floatx4*)(out + i + 4);
    int cc = b * D_ + col;
#pragma unroll
    for (int j = 0; j < 4; ++j) {
      a0[j] = a0[j] * scale[cc + j] + shift[cc + j];
      a1[j] = a1[j] * scale[cc + 4 + j] + shift[cc + 4 + j];
    }
    *(floatx4*)(out + i)     = a0;
    *(floatx4*)(out + i + 4) = a1;
  }
}

extern "C" void kernel_launch(void* const* d_in, const int* in_sizes, int n_in,
                              void* d_out, int out_size, void* d_ws, size_t ws_size,
                              hipStream_t stream) {
  // inputs: 0 batch_size(i32), 1 num_customers(i32), 2 tour_index(i32),
  // 3 embeddings(f32), 4 W1(f32), 5 b1(f32), 6 W2(f32), 7 b2(f32),
  // 8 gamma(f32), 9 beta(f32)
  const int*   tour_index = (const int*)d_in[2];
  const float* emb   = (const float*)d_in[3];
  const float* W1    = (const float*)d_in[4];
  const float* b1    = (const float*)d_in[5];
  const float* W2    = (const float*)d_in[6];
  const float* b2    = (const float*)d_in[7];
  const float* gamma = (const float*)d_in[8];
  const float* beta  = (const float*)d_in[9];
  float* out = (float*)d_out;
  char* ws = (char*)d_ws;

  // ws layout (total ~3.5 MB):
  u16*   w1f   = (u16*)(ws);                 //    65,536 B
  u16*   w2f   = (u16*)(ws + 65536);         //    32,768 B
  u16*   tourb = (u16*)(ws + 98304);         // 3,276,800 B (bf16 tour table)
  float* ssum  = (float*)(ws + 3375104);     //    65,536 B (ssum || ssq)
  float* ssq   = ssum + B_ * D_;
  float* scale = (float*)(ws + 3440640);     //    65,536 B (scale || shift)
  float* shift = scale + B_ * D_;

  hipLaunchKernelGGL(k_zero,   dim3(64),    dim3(256), 0, stream, ssum, 2 * B_ * D_);
  hipLaunchKernelGGL(k_prep_w, dim3(24),    dim3(256), 0, stream, W1, W2, w1f, w2f);
  hipLaunchKernelGGL(k_segsum, dim3(2, 64), dim3(256), 0, stream, tour_index, emb, tourb);
  hipLaunchKernelGGL(k_mlp,    dim3(1000),  dim3(256), 0, stream, tour_index, emb, tourb,
                     w1f, w2f, b1, b2, out);
  hipLaunchKernelGGL(k_stats,  dim3(8, 64), dim3(256), 0, stream, out, ssum, ssq);
  hipLaunchKernelGGL(k_final,  dim3(32),    dim3(256), 0, stream, ssum, ssq, gamma, beta,
                     scale, shift);
  hipLaunchKernelGGL(k_out,    dim3(8004),  dim3(256), 0, stream, emb, scale, shift, out);
}

// Round 4
// 315.766 us; speedup vs baseline: 1.3294x; 1.3294x over previous
//
#include <hip/hip_runtime.h>
#include <stdint.h>

typedef unsigned short u16;
typedef __attribute__((ext_vector_type(8))) short short8;
typedef __attribute__((ext_vector_type(4))) short short4v;
typedef __attribute__((ext_vector_type(4))) float floatx4;

constexpr int B_ = 64, P_ = 2000, D_ = 128, T_ = 200;

__device__ __forceinline__ u16 f2bf(float f) {
  union { float f; uint32_t u; } v; v.f = f;
  return (u16)((v.u + 0x7fffu + ((v.u >> 16) & 1u)) >> 16);
}

// ---- zero tourf + ssum + ssq (contiguous span; ws is poisoned 0xAA) ----
__global__ void k_zero(float* __restrict__ p, int n) {
  int i = blockIdx.x * 256 + threadIdx.x;
  if (i < n) p[i] = 0.f;
}

// ---- pack fp32 W1 (256x128) / W2 (128x128) into bf16 MFMA B-fragment order ----
// frag id = (ks*8 + nt)*64 + lane ; lane holds B[k0+j][nt*16 + (lane&15)], j=0..7,
// k0 = ks*32 + (lane>>4)*8.  W1: 8 ksteps (4096 frags). W2: 4 ksteps (2048 frags).
__global__ void k_prep_w(const float* __restrict__ W1, const float* __restrict__ W2,
                         u16* __restrict__ w1f, u16* __restrict__ w2f) {
  int tid = blockIdx.x * 256 + threadIdx.x;
  if (tid >= 6144) return;
  const float* W = (tid < 4096) ? W1 : W2;
  u16* dst = (tid < 4096) ? w1f : w2f;
  int fid = (tid < 4096) ? tid : tid - 4096;
  int lane = fid & 63;
  int nt = (fid >> 6) & 7;
  int ks = fid >> 9;
  int quad = lane >> 4, c = lane & 15;
  int k0 = ks * 32 + quad * 8;
#pragma unroll
  for (int j = 0; j < 8; ++j)
    dst[(size_t)fid * 8 + j] = f2bf(W[(k0 + j) * D_ + nt * 16 + c]);
}

// ---- segment sum, latency-optimized ----
// grid (4, 64): x = dhalf(2) * psplit(2), y = batch. 512 threads = 8 waves.
// Wave wv handles rows p = wv (mod 8) of its 1000-row psplit: 125 rows, in
// chunks of 5 -> 10 independent global loads in flight before the LDS adds.
// Block result is merged into the global fp32 table via atomicAdd.
__global__ __launch_bounds__(512) void k_segsum(const int* __restrict__ tidx,
                                                const float* __restrict__ emb,
                                                float* __restrict__ tourf) {
  __shared__ float acc[T_ * 64];
  const int b = blockIdx.y;
  const int dh = blockIdx.x & 1, ps = blockIdx.x >> 1;
  const int tid = threadIdx.x;
  for (int i = tid; i < T_ * 64; i += 512) acc[i] = 0.f;
  __syncthreads();
  const int d = tid & 63, wv = tid >> 6;
  const float* eb = emb + ((size_t)b * 2001 + 1 + ps * 1000) * D_ + dh * 64 + d;
  const int* ti = tidx + b * P_ + ps * 1000;
  for (int cch = 0; cch < 25; ++cch) {
    int pb = wv + cch * 40;
    int t[5]; float v[5];
#pragma unroll
    for (int j = 0; j < 5; ++j) t[j] = ti[pb + j * 8];
#pragma unroll
    for (int j = 0; j < 5; ++j) v[j] = eb[(size_t)(pb + j * 8) * D_];
#pragma unroll
    for (int j = 0; j < 5; ++j) atomicAdd(&acc[t[j] * 64 + d], v[j]);
  }
  __syncthreads();
  float* dst = tourf + (size_t)b * T_ * D_ + dh * 64;
  for (int i = tid; i < T_ * 64; i += 512)
    atomicAdd(&dst[(size_t)(i >> 6) * D_ + (i & 63)], acc[i]);
}

// ---- convert fp32 tour table -> bf16 (1600 blocks * 256 thr * 4 elems exact) ----
__global__ void k_conv(const float* __restrict__ tourf, u16* __restrict__ tourb) {
  int i = (blockIdx.x * 256 + threadIdx.x) * 4;
  floatx4 x = *(const floatx4*)(tourf + i);
  short4v r;
#pragma unroll
  for (int j = 0; j < 4; ++j) r[j] = (short)f2bf(x[j]);
  *(short4v*)(tourb + i) = r;
}

// ---- fused MLP: h = relu(x@W1+b1); h = h@W2+b2; out[b,1+p,:] = cust + h ----
// 1000 blocks x 128 rows. 4 waves, each 32 rows (2x 16-row tiles) x 128 cols (8x 16).
// GEMMs in bf16 MFMA; residual add + store in fp32.
__global__ __launch_bounds__(256) void k_mlp(
    const int* __restrict__ tidx, const float* __restrict__ emb,
    const u16* __restrict__ tourb,
    const u16* __restrict__ w1f, const u16* __restrict__ w2f,
    const float* __restrict__ b1, const float* __restrict__ b2,
    float* __restrict__ out) {
  __shared__ u16 hbuf[128 * 136];  // stride 136: 16B-aligned rows, 2-way banks (free)
  const int tid = threadIdx.x;
  const int w = tid >> 6, lane = tid & 63, quad = lane >> 4, c = lane & 15;
  const int base = blockIdx.x * 128;
  const int r0 = w * 32;

  const float* arow[2];
  const u16* trow[2];
#pragma unroll
  for (int mt = 0; mt < 2; ++mt) {
    int m = base + r0 + mt * 16 + c;
    int b = m / P_, p = m - b * P_;
    arow[mt] = emb + ((size_t)(b * 2001 + 1 + p)) * D_;
    int t = tidx[m];
    trow[mt] = tourb + ((size_t)(b * T_ + t)) * D_;
  }
  float bias1[8], bias2[8];
#pragma unroll
  for (int nt = 0; nt < 8; ++nt) {
    bias1[nt] = b1[nt * 16 + c];
    bias2[nt] = b2[nt * 16 + c];
  }

  // ---- GEMM1: K=256 (cust fp32->bf16 k 0..127, tour bf16 k 128..255) ----
  floatx4 acc[2][8];
#pragma unroll
  for (int mt = 0; mt < 2; ++mt)
#pragma unroll
    for (int nt = 0; nt < 8; ++nt) acc[mt][nt] = (floatx4)0.f;

#pragma unroll
  for (int ks = 0; ks < 8; ++ks) {
    short8 a[2];
#pragma unroll
    for (int mt = 0; mt < 2; ++mt) {
      if (ks < 4) {
        const float* src = arow[mt] + ks * 32 + quad * 8;
        floatx4 x0 = *(const floatx4*)src;
        floatx4 x1 = *(const floatx4*)(src + 4);
#pragma unroll
        for (int j = 0; j < 4; ++j) {
          a[mt][j]     = (short)f2bf(x0[j]);
          a[mt][4 + j] = (short)f2bf(x1[j]);
        }
      } else {
        a[mt] = *(const short8*)(trow[mt] + (ks - 4) * 32 + quad * 8);
      }
    }
#pragma unroll
    for (int nt = 0; nt < 8; ++nt) {
      short8 bf = *(const short8*)(w1f + ((size_t)((ks * 8 + nt) * 64 + lane)) * 8);
      acc[0][nt] = __builtin_amdgcn_mfma_f32_16x16x32_bf16(a[0], bf, acc[0][nt], 0, 0, 0);
      acc[1][nt] = __builtin_amdgcn_mfma_f32_16x16x32_bf16(a[1], bf, acc[1][nt], 0, 0, 0);
    }
  }

  // epilogue 1: relu(acc + b1) -> hbuf bf16 (C layout: row = quad*4+r, col = lane&15)
#pragma unroll
  for (int mt = 0; mt < 2; ++mt)
#pragma unroll
    for (int nt = 0; nt < 8; ++nt)
#pragma unroll
      for (int r = 0; r < 4; ++r) {
        int row = r0 + mt * 16 + quad * 4 + r;
        float v = acc[mt][nt][r] + bias1[nt];
        hbuf[row * 136 + nt * 16 + c] = f2bf(v > 0.f ? v : 0.f);
      }
  __syncthreads();

  // ---- GEMM2: K=128, A-frags from hbuf ----
  floatx4 acc2[2][8];
#pragma unroll
  for (int mt = 0; mt < 2; ++mt)
#pragma unroll
    for (int nt = 0; nt < 8; ++nt) acc2[mt][nt] = (floatx4)0.f;

#pragma unroll
  for (int ks = 0; ks < 4; ++ks) {
    short8 a[2];
#pragma unroll
    for (int mt = 0; mt < 2; ++mt)
      a[mt] = *(const short8*)(&hbuf[(r0 + mt * 16 + c) * 136 + ks * 32 + quad * 8]);
#pragma unroll
    for (int nt = 0; nt < 8; ++nt) {
      short8 bf = *(const short8*)(w2f + ((size_t)((ks * 8 + nt) * 64 + lane)) * 8);
      acc2[0][nt] = __builtin_amdgcn_mfma_f32_16x16x32_bf16(a[0], bf, acc2[0][nt], 0, 0, 0);
      acc2[1][nt] = __builtin_amdgcn_mfma_f32_16x16x32_bf16(a[1], bf, acc2[1][nt], 0, 0, 0);
    }
  }

  // epilogue 2: out[b,1+p,col] = cust(fp32) + (acc2 + b2); C-layout stores:
  // lanes c=0..15 of a quad write 16 consecutive fp32 = 64B segments (efficient).
#pragma unroll
  for (int mt = 0; mt < 2; ++mt)
#pragma unroll
    for (int nt = 0; nt < 8; ++nt)
#pragma unroll
      for (int r = 0; r < 4; ++r) {
        int row = r0 + mt * 16 + quad * 4 + r;
        int m = base + row;
        int b = m / P_, p = m - b * P_;
        size_t gaddr = ((size_t)(b * 2001 + 1 + p)) * D_ + nt * 16 + c;
        out[gaddr] = emb[gaddr] + (acc2[mt][nt][r] + bias2[nt]);
      }
}

// ---- per-(b,d) sum / sumsq over the P rows of `out`. grid (8, 64) ----
__global__ __launch_bounds__(256) void k_stats(const float* __restrict__ out,
                                               float* __restrict__ ssum,
                                               float* __restrict__ ssq) {
  const int b = blockIdx.y, ps = blockIdx.x;
  const int tid = threadIdx.x;
  const int col = tid & 127, rh = tid >> 7;
  float s = 0.f, s2 = 0.f;
  const float* src = out + ((size_t)b * 2001 + 1) * D_ + col;
  for (int p = ps * 250 + rh; p < ps * 250 + 250; p += 2) {
    float v = src[(size_t)p * D_];
    s += v; s2 += v * v;
  }
  __shared__ float ls[128], ls2[128];
  if (rh == 0) { ls[col] = s; ls2[col] = s2; }
  __syncthreads();
  if (rh == 1) { ls[col] += s; ls2[col] += s2; }
  __syncthreads();
  if (rh == 0) {
    atomicAdd(&ssum[b * D_ + col], ls[col]);
    atomicAdd(&ssq[b * D_ + col], ls2[col]);
  }
}

// ---- finalize: scale = rstd*gamma, shift = beta - mean*scale ----
__global__ void k_final(const float* __restrict__ ssum, const float* __restrict__ ssq,
                        const float* __restrict__ gamma, const float* __restrict__ beta,
                        float* __restrict__ scale, float* __restrict__ shift) {
  int i = blockIdx.x * 256 + threadIdx.x;
  if (i >= B_ * D_) return;
  int col = i & 127;
  float mean = ssum[i] * (1.f / P_);
  float var = ssq[i] * (1.f / P_) - mean * mean;
  float rstd = rsqrtf(var + 1e-5f);
  float sc = rstd * gamma[col];
  scale[i] = sc;
  shift[i] = beta[col] - mean * sc;
}

// ---- in-place normalize + depot-row copy. 8004 blocks * 256 thr * 8 elems exact ----
__global__ __launch_bounds__(256) void k_out(
    const float* __restrict__ emb,
    const float* __restrict__ scale, const float* __restrict__ shift,
    float* __restrict__ out) {
  size_t i = ((size_t)blockIdx.x * 256 + threadIdx.x) * 8;
  int row = (int)(i >> 7), col = (int)(i & 127);
  int b = row / 2001, r = row - b * 2001;
  if (r == 0) {
    *(floatx4*)(out + i)     = *(const floatx4*)(emb + i);
    *(floatx4*)(out + i + 4) = *(const floatx4*)(emb + i + 4);
  } else {
    floatx4 a0 = *(const floatx4*)(out + i);
    floatx4 a1 = *(const floatx4*)(out + i + 4);
    int cc = b * D_ + col;
#pragma unroll
    for (int j = 0; j < 4; ++j) {
      a0[j] = a0[j] * scale[cc + j] + shift[cc + j];
      a1[j] = a1[j] * scale[cc + 4 + j] + shift[cc + 4 + j];
    }
    *(floatx4*)(out + i)     = a0;
    *(floatx4*)(out + i + 4) = a1;
  }
}

extern "C" void kernel_launch(void* const* d_in, const int* in_sizes, int n_in,
                              void* d_out, int out_size, void* d_ws, size_t ws_size,
                              hipStream_t stream) {
  // inputs: 0 batch_size(i32), 1 num_customers(i32), 2 tour_index(i32),
  // 3 embeddings(f32), 4 W1(f32), 5 b1(f32), 6 W2(f32), 7 b2(f32),
  // 8 gamma(f32), 9 beta(f32)
  const int*   tour_index = (const int*)d_in[2];
  const float* emb   = (const float*)d_in[3];
  const float* W1    = (const float*)d_in[4];
  const float* b1    = (const float*)d_in[5];
  const float* W2    = (const float*)d_in[6];
  const float* b2    = (const float*)d_in[7];
  const float* gamma = (const float*)d_in[8];
  const float* beta  = (const float*)d_in[9];
  float* out = (float*)d_out;
  char* ws = (char*)d_ws;

  // ws layout (total ~10.1 MB):
  u16*   w1f   = (u16*)(ws);                 //    65,536 B
  u16*   w2f   = (u16*)(ws + 65536);         //    32,768 B
  float* tourf = (float*)(ws + 98304);       // 6,553,600 B (fp32 tour accumulator)
  float* ssum  = (float*)(ws + 6651904);     //    65,536 B (ssum || ssq)
  float* ssq   = ssum + B_ * D_;
  float* scale = (float*)(ws + 6717440);     //    65,536 B (scale || shift)
  float* shift = scale + B_ * D_;
  u16*   tourb = (u16*)(ws + 6782976);       // 3,276,800 B (bf16 tour table)

  // zero tourf + ssum + ssq in one contiguous pass: 1,654,784 floats = 6464*256
  hipLaunchKernelGGL(k_zero,   dim3(6464),  dim3(256), 0, stream, tourf, 1654784);
  hipLaunchKernelGGL(k_prep_w, dim3(24),    dim3(256), 0, stream, W1, W2, w1f, w2f);
  hipLaunchKernelGGL(k_segsum, dim3(4, 64), dim3(512), 0, stream, tour_index, emb, tourf);
  hipLaunchKernelGGL(k_conv,   dim3(1600),  dim3(256), 0, stream, tourf, tourb);
  hipLaunchKernelGGL(k_mlp,    dim3(1000),  dim3(256), 0, stream, tour_index, emb, tourb,
                     w1f, w2f, b1, b2, out);
  hipLaunchKernelGGL(k_stats,  dim3(8, 64), dim3(256), 0, stream, out, ssum, ssq);
  hipLaunchKernelGGL(k_final,  dim3(32),    dim3(256), 0, stream, ssum, ssq, gamma, beta,
                     scale, shift);
  hipLaunchKernelGGL(k_out,    dim3(8004),  dim3(256), 0, stream, emb, scale, shift, out);
}

// Round 5
// 308.783 us; speedup vs baseline: 1.3594x; 1.0226x over previous
//
#include <hip/hip_runtime.h>
#include <stdint.h>

typedef unsigned short u16;
typedef __attribute__((ext_vector_type(8))) short short8;
typedef __attribute__((ext_vector_type(4))) short short4v;
typedef __attribute__((ext_vector_type(4))) float floatx4;

constexpr int B_ = 64, P_ = 2000, D_ = 128, T_ = 200;

__device__ __forceinline__ u16 f2bf(float f) {
  union { float f; uint32_t u; } v; v.f = f;
  return (u16)((v.u + 0x7fffu + ((v.u >> 16) & 1u)) >> 16);
}

// ---- zero tourf + ssum + ssq (contiguous span; ws is poisoned 0xAA) ----
__global__ void k_zero(float* __restrict__ p, int n) {
  int i = blockIdx.x * 256 + threadIdx.x;
  if (i < n) p[i] = 0.f;
}

// ---- pack fp32 W1 (256x128) / W2 (128x128) into bf16 MFMA B-fragment order ----
// frag id = (ks*8 + nt)*64 + lane ; lane holds B[k0+j][nt*16 + (lane&15)], j=0..7,
// k0 = ks*32 + (lane>>4)*8.  W1: 8 ksteps (4096 frags). W2: 4 ksteps (2048 frags).
__global__ void k_prep_w(const float* __restrict__ W1, const float* __restrict__ W2,
                         u16* __restrict__ w1f, u16* __restrict__ w2f) {
  int tid = blockIdx.x * 256 + threadIdx.x;
  if (tid >= 6144) return;
  const float* W = (tid < 4096) ? W1 : W2;
  u16* dst = (tid < 4096) ? w1f : w2f;
  int fid = (tid < 4096) ? tid : tid - 4096;
  int lane = fid & 63;
  int nt = (fid >> 6) & 7;
  int ks = fid >> 9;
  int quad = lane >> 4, c = lane & 15;
  int k0 = ks * 32 + quad * 8;
#pragma unroll
  for (int j = 0; j < 8; ++j)
    dst[(size_t)fid * 8 + j] = f2bf(W[(k0 + j) * D_ + nt * 16 + c]);
}

// ---- segment sum v3: t from LDS, v-only global chain, full-D blocks ----
// grid (4, 64): x = psplit(4), y = batch. 512 threads = 8 waves. Each block:
// 500 rows, full 128-d (lane = float2). Wave wv takes rows wv + 8*i; chunks of
// 8 rows in flight (only v loads in the chain — t comes from LDS tcache).
// Block LDS table merges into global tourf via atomicAdd.
__global__ __launch_bounds__(512) void k_segsum(const int* __restrict__ tidx,
                                                const float* __restrict__ emb,
                                                float* __restrict__ tourf) {
  __shared__ float acc[T_ * D_];   // 102,400 B
  __shared__ int tc[500];
  const int b = blockIdx.y, ps = blockIdx.x;
  const int tid = threadIdx.x;
  for (int i = tid; i < T_ * D_; i += 512) acc[i] = 0.f;
  if (tid < 500) tc[tid] = tidx[b * P_ + ps * 500 + tid];
  __syncthreads();
  const int lane = tid & 63, wv = tid >> 6;
  const float* eb = emb + ((size_t)(b * 2001 + 1 + ps * 500)) * D_ + lane * 2;
  for (int c = 0; c < 8; ++c) {
    float2 v[8]; int t[8];
#pragma unroll
    for (int j = 0; j < 8; ++j) {
      int r = wv + 64 * c + 8 * j;
      if (r < 500) v[j] = *(const float2*)(eb + (size_t)r * D_);
    }
#pragma unroll
    for (int j = 0; j < 8; ++j) {
      int r = wv + 64 * c + 8 * j;
      if (r < 500) t[j] = tc[r];
    }
#pragma unroll
    for (int j = 0; j < 8; ++j) {
      int r = wv + 64 * c + 8 * j;
      if (r < 500) {
        atomicAdd(&acc[t[j] * D_ + lane * 2], v[j].x);
        atomicAdd(&acc[t[j] * D_ + lane * 2 + 1], v[j].y);
      }
    }
  }
  __syncthreads();
  float* dst = tourf + (size_t)b * T_ * D_;
  for (int i = tid; i < T_ * D_; i += 512)
    atomicAdd(&dst[i], acc[i]);
}

// ---- convert fp32 tour table -> bf16 (1600 blocks * 256 thr * 4 elems exact) ----
__global__ void k_conv(const float* __restrict__ tourf, u16* __restrict__ tourb) {
  int i = (blockIdx.x * 256 + threadIdx.x) * 4;
  floatx4 x = *(const floatx4*)(tourf + i);
  short4v r;
#pragma unroll
  for (int j = 0; j < 4; ++j) r[j] = (short)f2bf(x[j]);
  *(short4v*)(tourb + i) = r;
}

// ---- fused MLP: h = relu(x@W1+b1); h = h@W2+b2; out[b,1+p,:] = cust + h ----
// 1000 blocks x 128 rows. 4 waves, each 32 rows (2x 16-row tiles) x 128 cols (8x 16).
// GEMMs in bf16 MFMA; residual add + store in fp32.
__global__ __launch_bounds__(256) void k_mlp(
    const int* __restrict__ tidx, const float* __restrict__ emb,
    const u16* __restrict__ tourb,
    const u16* __restrict__ w1f, const u16* __restrict__ w2f,
    const float* __restrict__ b1, const float* __restrict__ b2,
    float* __restrict__ out) {
  __shared__ u16 hbuf[128 * 136];  // stride 136: 16B-aligned rows, 2-way banks (free)
  const int tid = threadIdx.x;
  const int w = tid >> 6, lane = tid & 63, quad = lane >> 4, c = lane & 15;
  const int base = blockIdx.x * 128;
  const int r0 = w * 32;

  const float* arow[2];
  const u16* trow[2];
#pragma unroll
  for (int mt = 0; mt < 2; ++mt) {
    int m = base + r0 + mt * 16 + c;
    int b = m / P_, p = m - b * P_;
    arow[mt] = emb + ((size_t)(b * 2001 + 1 + p)) * D_;
    int t = tidx[m];
    trow[mt] = tourb + ((size_t)(b * T_ + t)) * D_;
  }
  float bias1[8], bias2[8];
#pragma unroll
  for (int nt = 0; nt < 8; ++nt) {
    bias1[nt] = b1[nt * 16 + c];
    bias2[nt] = b2[nt * 16 + c];
  }

  // ---- GEMM1: K=256 (cust fp32->bf16 k 0..127, tour bf16 k 128..255) ----
  floatx4 acc[2][8];
#pragma unroll
  for (int mt = 0; mt < 2; ++mt)
#pragma unroll
    for (int nt = 0; nt < 8; ++nt) acc[mt][nt] = (floatx4)0.f;

#pragma unroll
  for (int ks = 0; ks < 8; ++ks) {
    short8 a[2];
#pragma unroll
    for (int mt = 0; mt < 2; ++mt) {
      if (ks < 4) {
        const float* src = arow[mt] + ks * 32 + quad * 8;
        floatx4 x0 = *(const floatx4*)src;
        floatx4 x1 = *(const floatx4*)(src + 4);
#pragma unroll
        for (int j = 0; j < 4; ++j) {
          a[mt][j]     = (short)f2bf(x0[j]);
          a[mt][4 + j] = (short)f2bf(x1[j]);
        }
      } else {
        a[mt] = *(const short8*)(trow[mt] + (ks - 4) * 32 + quad * 8);
      }
    }
#pragma unroll
    for (int nt = 0; nt < 8; ++nt) {
      short8 bf = *(const short8*)(w1f + ((size_t)((ks * 8 + nt) * 64 + lane)) * 8);
      acc[0][nt] = __builtin_amdgcn_mfma_f32_16x16x32_bf16(a[0], bf, acc[0][nt], 0, 0, 0);
      acc[1][nt] = __builtin_amdgcn_mfma_f32_16x16x32_bf16(a[1], bf, acc[1][nt], 0, 0, 0);
    }
  }

  // epilogue 1: relu(acc + b1) -> hbuf bf16 (C layout: row = quad*4+r, col = lane&15)
#pragma unroll
  for (int mt = 0; mt < 2; ++mt)
#pragma unroll
    for (int nt = 0; nt < 8; ++nt)
#pragma unroll
      for (int r = 0; r < 4; ++r) {
        int row = r0 + mt * 16 + quad * 4 + r;
        float v = acc[mt][nt][r] + bias1[nt];
        hbuf[row * 136 + nt * 16 + c] = f2bf(v > 0.f ? v : 0.f);
      }
  __syncthreads();

  // ---- GEMM2: K=128, A-frags from hbuf ----
  floatx4 acc2[2][8];
#pragma unroll
  for (int mt = 0; mt < 2; ++mt)
#pragma unroll
    for (int nt = 0; nt < 8; ++nt) acc2[mt][nt] = (floatx4)0.f;

#pragma unroll
  for (int ks = 0; ks < 4; ++ks) {
    short8 a[2];
#pragma unroll
    for (int mt = 0; mt < 2; ++mt)
      a[mt] = *(const short8*)(&hbuf[(r0 + mt * 16 + c) * 136 + ks * 32 + quad * 8]);
#pragma unroll
    for (int nt = 0; nt < 8; ++nt) {
      short8 bf = *(const short8*)(w2f + ((size_t)((ks * 8 + nt) * 64 + lane)) * 8);
      acc2[0][nt] = __builtin_amdgcn_mfma_f32_16x16x32_bf16(a[0], bf, acc2[0][nt], 0, 0, 0);
      acc2[1][nt] = __builtin_amdgcn_mfma_f32_16x16x32_bf16(a[1], bf, acc2[1][nt], 0, 0, 0);
    }
  }

  // epilogue 2: out[b,1+p,col] = cust(fp32) + (acc2 + b2); C-layout stores:
  // lanes c=0..15 of a quad write 16 consecutive fp32 = 64B segments (efficient).
#pragma unroll
  for (int mt = 0; mt < 2; ++mt)
#pragma unroll
    for (int nt = 0; nt < 8; ++nt)
#pragma unroll
      for (int r = 0; r < 4; ++r) {
        int row = r0 + mt * 16 + quad * 4 + r;
        int m = base + row;
        int b = m / P_, p = m - b * P_;
        size_t gaddr = ((size_t)(b * 2001 + 1 + p)) * D_ + nt * 16 + c;
        out[gaddr] = emb[gaddr] + (acc2[mt][nt][r] + bias2[nt]);
      }
}

// ---- per-(b,d) sum / sumsq over the P rows of `out`. grid (16, 64) ----
__global__ __launch_bounds__(256) void k_stats(const float* __restrict__ out,
                                               float* __restrict__ ssum,
                                               float* __restrict__ ssq) {
  const int b = blockIdx.y, ps = blockIdx.x;
  const int tid = threadIdx.x;
  const int col = tid & 127, rh = tid >> 7;
  float s = 0.f, s2 = 0.f;
  const float* src = out + ((size_t)b * 2001 + 1) * D_ + col;
  for (int p = ps * 125 + rh; p < ps * 125 + 125; p += 2) {
    float v = src[(size_t)p * D_];
    s += v; s2 += v * v;
  }
  __shared__ float ls[128], ls2[128];
  if (rh == 0) { ls[col] = s; ls2[col] = s2; }
  __syncthreads();
  if (rh == 1) { ls[col] += s; ls2[col] += s2; }
  __syncthreads();
  if (rh == 0) {
    atomicAdd(&ssum[b * D_ + col], ls[col]);
    atomicAdd(&ssq[b * D_ + col], ls2[col]);
  }
}

// ---- finalize: scale = rstd*gamma, shift = beta - mean*scale ----
__global__ void k_final(const float* __restrict__ ssum, const float* __restrict__ ssq,
                        const float* __restrict__ gamma, const float* __restrict__ beta,
                        float* __restrict__ scale, float* __restrict__ shift) {
  int i = blockIdx.x * 256 + threadIdx.x;
  if (i >= B_ * D_) return;
  int col = i & 127;
  float mean = ssum[i] * (1.f / P_);
  float var = ssq[i] * (1.f / P_) - mean * mean;
  float rstd = rsqrtf(var + 1e-5f);
  float sc = rstd * gamma[col];
  scale[i] = sc;
  shift[i] = beta[col] - mean * sc;
}

// ---- in-place normalize + depot-row copy. 8004 blocks * 256 thr * 8 elems exact ----
__global__ __launch_bounds__(256) void k_out(
    const float* __restrict__ emb,
    const float* __restrict__ scale, const float* __restrict__ shift,
    float* __restrict__ out) {
  size_t i = ((size_t)blockIdx.x * 256 + threadIdx.x) * 8;
  int row = (int)(i >> 7), col = (int)(i & 127);
  int b = row / 2001, r = row - b * 2001;
  if (r == 0) {
    *(floatx4*)(out + i)     = *(const floatx4*)(emb + i);
    *(floatx4*)(out + i + 4) = *(const floatx4*)(emb + i + 4);
  } else {
    floatx4 a0 = *(const floatx4*)(out + i);
    floatx4 a1 = *(const floatx4*)(out + i + 4);
    int cc = b * D_ + col;
#pragma unroll
    for (int j = 0; j < 4; ++j) {
      a0[j] = a0[j] * scale[cc + j] + shift[cc + j];
      a1[j] = a1[j] * scale[cc + 4 + j] + shift[cc + 4 + j];
    }
    *(floatx4*)(out + i)     = a0;
    *(floatx4*)(out + i + 4) = a1;
  }
}

extern "C" void kernel_launch(void* const* d_in, const int* in_sizes, int n_in,
                              void* d_out, int out_size, void* d_ws, size_t ws_size,
                              hipStream_t stream) {
  // inputs: 0 batch_size(i32), 1 num_customers(i32), 2 tour_index(i32),
  // 3 embeddings(f32), 4 W1(f32), 5 b1(f32), 6 W2(f32), 7 b2(f32),
  // 8 gamma(f32), 9 beta(f32)
  const int*   tour_index = (const int*)d_in[2];
  const float* emb   = (const float*)d_in[3];
  const float* W1    = (const float*)d_in[4];
  const float* b1    = (const float*)d_in[5];
  const float* W2    = (const float*)d_in[6];
  const float* b2    = (const float*)d_in[7];
  const float* gamma = (const float*)d_in[8];
  const float* beta  = (const float*)d_in[9];
  float* out = (float*)d_out;
  char* ws = (char*)d_ws;

  // ws layout (total ~10.1 MB):
  u16*   w1f   = (u16*)(ws);                 //    65,536 B
  u16*   w2f   = (u16*)(ws + 65536);         //    32,768 B
  float* tourf = (float*)(ws + 98304);       // 6,553,600 B (fp32 tour accumulator)
  float* ssum  = (float*)(ws + 6651904);     //    65,536 B (ssum || ssq)
  float* ssq   = ssum + B_ * D_;
  float* scale = (float*)(ws + 6717440);     //    65,536 B (scale || shift)
  float* shift = scale + B_ * D_;
  u16*   tourb = (u16*)(ws + 6782976);       // 3,276,800 B (bf16 tour table)

  // zero tourf + ssum + ssq in one contiguous pass: 1,654,784 floats = 6464*256
  hipLaunchKernelGGL(k_zero,   dim3(6464),   dim3(256), 0, stream, tourf, 1654784);
  hipLaunchKernelGGL(k_prep_w, dim3(24),     dim3(256), 0, stream, W1, W2, w1f, w2f);
  hipLaunchKernelGGL(k_segsum, dim3(4, 64),  dim3(512), 0, stream, tour_index, emb, tourf);
  hipLaunchKernelGGL(k_conv,   dim3(1600),   dim3(256), 0, stream, tourf, tourb);
  hipLaunchKernelGGL(k_mlp,    dim3(1000),   dim3(256), 0, stream, tour_index, emb, tourb,
                     w1f, w2f, b1, b2, out);
  hipLaunchKernelGGL(k_stats,  dim3(16, 64), dim3(256), 0, stream, out, ssum, ssq);
  hipLaunchKernelGGL(k_final,  dim3(32),     dim3(256), 0, stream, ssum, ssq, gamma, beta,
                     scale, shift);
  hipLaunchKernelGGL(k_out,    dim3(8004),   dim3(256), 0, stream, emb, scale, shift, out);
}

// Round 6
// 296.233 us; speedup vs baseline: 1.4170x; 1.0424x over previous
//
#include <hip/hip_runtime.h>
#include <stdint.h>

typedef unsigned short u16;
typedef __attribute__((ext_vector_type(8))) short short8;
typedef __attribute__((ext_vector_type(4))) short short4v;
typedef __attribute__((ext_vector_type(4))) float floatx4;

constexpr int B_ = 64, P_ = 2000, D_ = 128, T_ = 200;
constexpr int S_ = B_ * T_ * D_;  // one tour-partial table: 1,638,400 floats

__device__ __forceinline__ u16 f2bf(float f) {
  union { float f; uint32_t u; } v; v.f = f;
  return (u16)((v.u + 0x7fffu + ((v.u >> 16) & 1u)) >> 16);
}

// ---- zero ssum/ssq (ws is poisoned 0xAA before every launch) ----
__global__ void k_zero(float* __restrict__ p, int n) {
  int i = blockIdx.x * 256 + threadIdx.x;
  if (i < n) p[i] = 0.f;
}

// ---- pack fp32 W1 (256x128) / W2 (128x128) into bf16 MFMA B-fragment order ----
// frag id = (ks*8 + nt)*64 + lane ; lane holds B[k0+j][nt*16 + (lane&15)], j=0..7,
// k0 = ks*32 + (lane>>4)*8.  W1: 8 ksteps (4096 frags). W2: 4 ksteps (2048 frags).
__global__ void k_prep_w(const float* __restrict__ W1, const float* __restrict__ W2,
                         u16* __restrict__ w1f, u16* __restrict__ w2f) {
  int tid = blockIdx.x * 256 + threadIdx.x;
  if (tid >= 6144) return;
  const float* W = (tid < 4096) ? W1 : W2;
  u16* dst = (tid < 4096) ? w1f : w2f;
  int fid = (tid < 4096) ? tid : tid - 4096;
  int lane = fid & 63;
  int nt = (fid >> 6) & 7;
  int ks = fid >> 9;
  int quad = lane >> 4, c = lane & 15;
  int k0 = ks * 32 + quad * 8;
#pragma unroll
  for (int j = 0; j < 8; ++j)
    dst[(size_t)fid * 8 + j] = f2bf(W[(k0 + j) * D_ + nt * 16 + c]);
}

// ---- segment sum v4: LDS accumulate, PLAIN private-partial stores (no atomics) ----
// grid (4, 64): x = psplit(4), y = batch. 512 threads = 8 waves. Each block:
// 500 rows, full 128-d (lane = float2). Wave wv takes rows wv + 8*i; chunks of
// 8 rows in flight (t from LDS tcache -> v-only global chain). Block writes its
// private T*D partial table to tourf[ps] with float4 stores.
__global__ __launch_bounds__(512) void k_segsum(const int* __restrict__ tidx,
                                                const float* __restrict__ emb,
                                                float* __restrict__ tourf) {
  __shared__ float acc[T_ * D_];   // 102,400 B
  __shared__ int tc[500];
  const int b = blockIdx.y, ps = blockIdx.x;
  const int tid = threadIdx.x;
  for (int i = tid; i < T_ * D_; i += 512) acc[i] = 0.f;
  if (tid < 500) tc[tid] = tidx[b * P_ + ps * 500 + tid];
  __syncthreads();
  const int lane = tid & 63, wv = tid >> 6;
  const float* eb = emb + ((size_t)(b * 2001 + 1 + ps * 500)) * D_ + lane * 2;
  for (int c = 0; c < 8; ++c) {
    float2 v[8]; int t[8];
#pragma unroll
    for (int j = 0; j < 8; ++j) {
      int r = wv + 64 * c + 8 * j;
      if (r < 500) v[j] = *(const float2*)(eb + (size_t)r * D_);
    }
#pragma unroll
    for (int j = 0; j < 8; ++j) {
      int r = wv + 64 * c + 8 * j;
      if (r < 500) t[j] = tc[r];
    }
#pragma unroll
    for (int j = 0; j < 8; ++j) {
      int r = wv + 64 * c + 8 * j;
      if (r < 500) {
        atomicAdd(&acc[t[j] * D_ + lane * 2], v[j].x);
        atomicAdd(&acc[t[j] * D_ + lane * 2 + 1], v[j].y);
      }
    }
  }
  __syncthreads();
  float* dst = tourf + (size_t)ps * S_ + (size_t)b * T_ * D_;
  for (int i = tid; i < T_ * D_ / 4; i += 512)
    ((floatx4*)dst)[i] = ((const floatx4*)acc)[i];
}

// ---- merge 4 partials + convert -> bf16 (1600 blocks * 256 thr * 4 elems) ----
__global__ void k_conv(const float* __restrict__ tourf, u16* __restrict__ tourb) {
  int i = (blockIdx.x * 256 + threadIdx.x) * 4;
  floatx4 x = *(const floatx4*)(tourf + i);
  floatx4 y = *(const floatx4*)(tourf + S_ + i);
  floatx4 z = *(const floatx4*)(tourf + 2 * S_ + i);
  floatx4 w = *(const floatx4*)(tourf + 3 * S_ + i);
  x = (x + y) + (z + w);
  short4v r;
#pragma unroll
  for (int j = 0; j < 4; ++j) r[j] = (short)f2bf(x[j]);
  *(short4v*)(tourb + i) = r;
}

// ---- fused MLP: h = relu(x@W1+b1); h = h@W2+b2; out[b,1+p,:] = cust + h ----
// 1000 blocks x 128 rows. 4 waves, each 32 rows (2x 16-row tiles) x 128 cols (8x 16).
// GEMMs in bf16 MFMA; residual add + store in fp32.
__global__ __launch_bounds__(256) void k_mlp(
    const int* __restrict__ tidx, const float* __restrict__ emb,
    const u16* __restrict__ tourb,
    const u16* __restrict__ w1f, const u16* __restrict__ w2f,
    const float* __restrict__ b1, const float* __restrict__ b2,
    float* __restrict__ out) {
  __shared__ u16 hbuf[128 * 136];  // stride 136: 16B-aligned rows, 2-way banks (free)
  const int tid = threadIdx.x;
  const int w = tid >> 6, lane = tid & 63, quad = lane >> 4, c = lane & 15;
  const int base = blockIdx.x * 128;
  const int r0 = w * 32;

  const float* arow[2];
  const u16* trow[2];
#pragma unroll
  for (int mt = 0; mt < 2; ++mt) {
    int m = base + r0 + mt * 16 + c;
    int b = m / P_, p = m - b * P_;
    arow[mt] = emb + ((size_t)(b * 2001 + 1 + p)) * D_;
    int t = tidx[m];
    trow[mt] = tourb + ((size_t)(b * T_ + t)) * D_;
  }
  float bias1[8], bias2[8];
#pragma unroll
  for (int nt = 0; nt < 8; ++nt) {
    bias1[nt] = b1[nt * 16 + c];
    bias2[nt] = b2[nt * 16 + c];
  }

  // ---- GEMM1: K=256 (cust fp32->bf16 k 0..127, tour bf16 k 128..255) ----
  floatx4 acc[2][8];
#pragma unroll
  for (int mt = 0; mt < 2; ++mt)
#pragma unroll
    for (int nt = 0; nt < 8; ++nt) acc[mt][nt] = (floatx4)0.f;

#pragma unroll
  for (int ks = 0; ks < 8; ++ks) {
    short8 a[2];
#pragma unroll
    for (int mt = 0; mt < 2; ++mt) {
      if (ks < 4) {
        const float* src = arow[mt] + ks * 32 + quad * 8;
        floatx4 x0 = *(const floatx4*)src;
        floatx4 x1 = *(const floatx4*)(src + 4);
#pragma unroll
        for (int j = 0; j < 4; ++j) {
          a[mt][j]     = (short)f2bf(x0[j]);
          a[mt][4 + j] = (short)f2bf(x1[j]);
        }
      } else {
        a[mt] = *(const short8*)(trow[mt] + (ks - 4) * 32 + quad * 8);
      }
    }
#pragma unroll
    for (int nt = 0; nt < 8; ++nt) {
      short8 bf = *(const short8*)(w1f + ((size_t)((ks * 8 + nt) * 64 + lane)) * 8);
      acc[0][nt] = __builtin_amdgcn_mfma_f32_16x16x32_bf16(a[0], bf, acc[0][nt], 0, 0, 0);
      acc[1][nt] = __builtin_amdgcn_mfma_f32_16x16x32_bf16(a[1], bf, acc[1][nt], 0, 0, 0);
    }
  }

  // epilogue 1: relu(acc + b1) -> hbuf bf16 (C layout: row = quad*4+r, col = lane&15)
#pragma unroll
  for (int mt = 0; mt < 2; ++mt)
#pragma unroll
    for (int nt = 0; nt < 8; ++nt)
#pragma unroll
      for (int r = 0; r < 4; ++r) {
        int row = r0 + mt * 16 + quad * 4 + r;
        float v = acc[mt][nt][r] + bias1[nt];
        hbuf[row * 136 + nt * 16 + c] = f2bf(v > 0.f ? v : 0.f);
      }
  __syncthreads();

  // ---- GEMM2: K=128, A-frags from hbuf ----
  floatx4 acc2[2][8];
#pragma unroll
  for (int mt = 0; mt < 2; ++mt)
#pragma unroll
    for (int nt = 0; nt < 8; ++nt) acc2[mt][nt] = (floatx4)0.f;

#pragma unroll
  for (int ks = 0; ks < 4; ++ks) {
    short8 a[2];
#pragma unroll
    for (int mt = 0; mt < 2; ++mt)
      a[mt] = *(const short8*)(&hbuf[(r0 + mt * 16 + c) * 136 + ks * 32 + quad * 8]);
#pragma unroll
    for (int nt = 0; nt < 8; ++nt) {
      short8 bf = *(const short8*)(w2f + ((size_t)((ks * 8 + nt) * 64 + lane)) * 8);
      acc2[0][nt] = __builtin_amdgcn_mfma_f32_16x16x32_bf16(a[0], bf, acc2[0][nt], 0, 0, 0);
      acc2[1][nt] = __builtin_amdgcn_mfma_f32_16x16x32_bf16(a[1], bf, acc2[1][nt], 0, 0, 0);
    }
  }

  // epilogue 2: out[b,1+p,col] = cust(fp32) + (acc2 + b2); C-layout stores:
  // lanes c=0..15 of a quad write 16 consecutive fp32 = 64B segments (efficient).
#pragma unroll
  for (int mt = 0; mt < 2; ++mt)
#pragma unroll
    for (int nt = 0; nt < 8; ++nt)
#pragma unroll
      for (int r = 0; r < 4; ++r) {
        int row = r0 + mt * 16 + quad * 4 + r;
        int m = base + row;
        int b = m / P_, p = m - b * P_;
        size_t gaddr = ((size_t)(b * 2001 + 1 + p)) * D_ + nt * 16 + c;
        out[gaddr] = emb[gaddr] + (acc2[mt][nt][r] + bias2[nt]);
      }
}

// ---- per-(b,d) sum / sumsq over the P rows of `out`. grid (16, 64) ----
__global__ __launch_bounds__(256) void k_stats(const float* __restrict__ out,
                                               float* __restrict__ ssum,
                                               float* __restrict__ ssq) {
  const int b = blockIdx.y, ps = blockIdx.x;
  const int tid = threadIdx.x;
  const int col = tid & 127, rh = tid >> 7;
  float s = 0.f, s2 = 0.f;
  const float* src = out + ((size_t)b * 2001 + 1) * D_ + col;
  for (int p = ps * 125 + rh; p < ps * 125 + 125; p += 2) {
    float v = src[(size_t)p * D_];
    s += v; s2 += v * v;
  }
  __shared__ float ls[128], ls2[128];
  if (rh == 0) { ls[col] = s; ls2[col] = s2; }
  __syncthreads();
  if (rh == 1) { ls[col] += s; ls2[col] += s2; }
  __syncthreads();
  if (rh == 0) {
    atomicAdd(&ssum[b * D_ + col], ls[col]);
    atomicAdd(&ssq[b * D_ + col], ls2[col]);
  }
}

// ---- finalize: scale = rstd*gamma, shift = beta - mean*scale ----
__global__ void k_final(const float* __restrict__ ssum, const float* __restrict__ ssq,
                        const float* __restrict__ gamma, const float* __restrict__ beta,
                        float* __restrict__ scale, float* __restrict__ shift) {
  int i = blockIdx.x * 256 + threadIdx.x;
  if (i >= B_ * D_) return;
  int col = i & 127;
  float mean = ssum[i] * (1.f / P_);
  float var = ssq[i] * (1.f / P_) - mean * mean;
  float rstd = rsqrtf(var + 1e-5f);
  float sc = rstd * gamma[col];
  scale[i] = sc;
  shift[i] = beta[col] - mean * sc;
}

// ---- in-place normalize + depot-row copy. 8004 blocks * 256 thr * 8 elems exact ----
__global__ __launch_bounds__(256) void k_out(
    const float* __restrict__ emb,
    const float* __restrict__ scale, const float* __restrict__ shift,
    float* __restrict__ out) {
  size_t i = ((size_t)blockIdx.x * 256 + threadIdx.x) * 8;
  int row = (int)(i >> 7), col = (int)(i & 127);
  int b = row / 2001, r = row - b * 2001;
  if (r == 0) {
    *(floatx4*)(out + i)     = *(const floatx4*)(emb + i);
    *(floatx4*)(out + i + 4) = *(const floatx4*)(emb + i + 4);
  } else {
    floatx4 a0 = *(const floatx4*)(out + i);
    floatx4 a1 = *(const floatx4*)(out + i + 4);
    int cc = b * D_ + col;
#pragma unroll
    for (int j = 0; j < 4; ++j) {
      a0[j] = a0[j] * scale[cc + j] + shift[cc + j];
      a1[j] = a1[j] * scale[cc + 4 + j] + shift[cc + 4 + j];
    }
    *(floatx4*)(out + i)     = a0;
    *(floatx4*)(out + i + 4) = a1;
  }
}

extern "C" void kernel_launch(void* const* d_in, const int* in_sizes, int n_in,
                              void* d_out, int out_size, void* d_ws, size_t ws_size,
                              hipStream_t stream) {
  // inputs: 0 batch_size(i32), 1 num_customers(i32), 2 tour_index(i32),
  // 3 embeddings(f32), 4 W1(f32), 5 b1(f32), 6 W2(f32), 7 b2(f32),
  // 8 gamma(f32), 9 beta(f32)
  const int*   tour_index = (const int*)d_in[2];
  const float* emb   = (const float*)d_in[3];
  const float* W1    = (const float*)d_in[4];
  const float* b1    = (const float*)d_in[5];
  const float* W2    = (const float*)d_in[6];
  const float* b2    = (const float*)d_in[7];
  const float* gamma = (const float*)d_in[8];
  const float* beta  = (const float*)d_in[9];
  float* out = (float*)d_out;
  char* ws = (char*)d_ws;

  // tour partials (4 x 6.55 MB = 26.2 MB) live in d_out — it's 65.6 MB and is
  // not produced until k_mlp; k_conv consumes the partials before that (same
  // stream, in-order). ws stays small (~3.4 MB).
  float* tourf = out;

  u16*   w1f   = (u16*)(ws);                 //    65,536 B
  u16*   w2f   = (u16*)(ws + 65536);         //    32,768 B
  float* ssum  = (float*)(ws + 98304);       //    65,536 B (ssum || ssq)
  float* ssq   = ssum + B_ * D_;
  float* scale = (float*)(ws + 163840);      //    65,536 B (scale || shift)
  float* shift = scale + B_ * D_;
  u16*   tourb = (u16*)(ws + 229376);        // 3,276,800 B (bf16 tour table)

  hipLaunchKernelGGL(k_zero,   dim3(64),     dim3(256), 0, stream, ssum, 2 * B_ * D_);
  hipLaunchKernelGGL(k_prep_w, dim3(24),     dim3(256), 0, stream, W1, W2, w1f, w2f);
  hipLaunchKernelGGL(k_segsum, dim3(4, 64),  dim3(512), 0, stream, tour_index, emb, tourf);
  hipLaunchKernelGGL(k_conv,   dim3(1600),   dim3(256), 0, stream, tourf, tourb);
  hipLaunchKernelGGL(k_mlp,    dim3(1000),   dim3(256), 0, stream, tour_index, emb, tourb,
                     w1f, w2f, b1, b2, out);
  hipLaunchKernelGGL(k_stats,  dim3(16, 64), dim3(256), 0, stream, out, ssum, ssq);
  hipLaunchKernelGGL(k_final,  dim3(32),     dim3(256), 0, stream, ssum, ssq, gamma, beta,
                     scale, shift);
  hipLaunchKernelGGL(k_out,    dim3(8004),   dim3(256), 0, stream, emb, scale, shift, out);
}

// Round 7
// 224.206 us; speedup vs baseline: 1.8722x; 1.3213x over previous
//
#include <hip/hip_runtime.h>
#include <stdint.h>

typedef unsigned short u16;
typedef __attribute__((ext_vector_type(8))) short short8;
typedef __attribute__((ext_vector_type(4))) float floatx4;

constexpr int B_ = 64, P_ = 2000, D_ = 128, T_ = 200;

__device__ __forceinline__ u16 f2bf(float f) {
  union { float f; uint32_t u; } v; v.f = f;
  return (u16)((v.u + 0x7fffu + ((v.u >> 16) & 1u)) >> 16);
}

// ---- zero ssum/ssq (ws is poisoned 0xAA before every launch) ----
__global__ void k_zero(float* __restrict__ p, int n) {
  int i = blockIdx.x * 256 + threadIdx.x;
  if (i < n) p[i] = 0.f;
}

// ---- pack fp32 W1 (256x128) / W2 (128x128) into bf16 MFMA B-fragment order ----
// frag id = (ks*8 + nt)*64 + lane ; lane holds B[k0+j][nt*16 + (lane&15)], j=0..7,
// k0 = ks*32 + (lane>>4)*8.  W1: 8 ksteps (4096 frags). W2: 4 ksteps (2048 frags).
__global__ void k_prep_w(const float* __restrict__ W1, const float* __restrict__ W2,
                         u16* __restrict__ w1f, u16* __restrict__ w2f) {
  int tid = blockIdx.x * 256 + threadIdx.x;
  if (tid >= 6144) return;
  const float* W = (tid < 4096) ? W1 : W2;
  u16* dst = (tid < 4096) ? w1f : w2f;
  int fid = (tid < 4096) ? tid : tid - 4096;
  int lane = fid & 63;
  int nt = (fid >> 6) & 7;
  int ks = fid >> 9;
  int quad = lane >> 4, c = lane & 15;
  int k0 = ks * 32 + quad * 8;
#pragma unroll
  for (int j = 0; j < 8; ++j)
    dst[(size_t)fid * 8 + j] = f2bf(W[(k0 + j) * D_ + nt * 16 + c]);
}

// ---- counting-sort customer ids by tour, per batch (scatter -> gather setup) ----
// grid 64 (one block per b), 256 threads. INT LDS atomics only (native/fast).
__global__ __launch_bounds__(256) void k_bin(const int* __restrict__ tidx,
                                             int* __restrict__ list,
                                             int* __restrict__ goff,
                                             int* __restrict__ gcnt) {
  __shared__ int tix[P_];
  __shared__ int cnt[256], scan[256], cur[256];
  const int b = blockIdx.x, tid = threadIdx.x;
  cnt[tid] = 0;
  for (int i = tid; i < P_; i += 256) tix[i] = tidx[b * P_ + i];
  __syncthreads();
  for (int i = tid; i < P_; i += 256) atomicAdd(&cnt[tix[i]], 1);
  __syncthreads();
  scan[tid] = cnt[tid];
  __syncthreads();
  for (int s = 1; s < 256; s <<= 1) {
    int v = (tid >= s) ? scan[tid - s] : 0;
    __syncthreads();
    scan[tid] += v;
    __syncthreads();
  }
  int excl = scan[tid] - cnt[tid];
  if (tid < T_) {
    goff[b * T_ + tid] = excl;
    gcnt[b * T_ + tid] = cnt[tid];
  }
  cur[tid] = excl;
  __syncthreads();
  for (int i = tid; i < P_; i += 256) {
    int slot = atomicAdd(&cur[tix[i]], 1);
    list[b * P_ + slot] = i;
  }
}

// ---- gather: one wave per (b,t) segment; register-sum its rows; bf16 write ----
// grid 3200 x 256 thr (4 waves): seg = blockIdx*4 + wave, 12,800 segments exact.
__global__ __launch_bounds__(256) void k_gather(const float* __restrict__ emb,
                                                const int* __restrict__ list,
                                                const int* __restrict__ goff,
                                                const int* __restrict__ gcnt,
                                                u16* __restrict__ tourb) {
  const int tid = threadIdx.x;
  const int lane = tid & 63, wv = tid >> 6;
  const int seg = blockIdx.x * 4 + wv;          // = b*T_ + t
  const int b = seg / T_;
  const int off = goff[seg], cn = gcnt[seg];
  const int* lstb = list + b * P_;
  const float* eb = emb + ((size_t)(b * 2001 + 1)) * D_ + lane * 2;
  float sx = 0.f, sy = 0.f;
  for (int i = 0; i < cn; i += 8) {
    int pr[8];
#pragma unroll
    for (int j = 0; j < 8; ++j)
      if (i + j < cn) pr[j] = lstb[off + i + j];
    float2 v[8];
#pragma unroll
    for (int j = 0; j < 8; ++j)
      if (i + j < cn) v[j] = *(const float2*)(eb + (size_t)pr[j] * D_);
#pragma unroll
    for (int j = 0; j < 8; ++j)
      if (i + j < cn) { sx += v[j].x; sy += v[j].y; }
  }
  uint32_t pk = (uint32_t)f2bf(sx) | ((uint32_t)f2bf(sy) << 16);
  ((uint32_t*)(tourb + (size_t)seg * D_))[lane] = pk;
}

// ---- fused MLP: h = relu(x@W1+b1); h = h@W2+b2; out[b,1+p,:] = cust + h ----
// 1000 blocks x 128 rows. 4 waves, each 32 rows (2x 16-row tiles) x 128 cols (8x 16).
// GEMMs in bf16 MFMA; residual add + store in fp32.
__global__ __launch_bounds__(256) void k_mlp(
    const int* __restrict__ tidx, const float* __restrict__ emb,
    const u16* __restrict__ tourb,
    const u16* __restrict__ w1f, const u16* __restrict__ w2f,
    const float* __restrict__ b1, const float* __restrict__ b2,
    float* __restrict__ out) {
  __shared__ u16 hbuf[128 * 136];  // stride 136: 16B-aligned rows, 2-way banks (free)
  const int tid = threadIdx.x;
  const int w = tid >> 6, lane = tid & 63, quad = lane >> 4, c = lane & 15;
  const int base = blockIdx.x * 128;
  const int r0 = w * 32;

  const float* arow[2];
  const u16* trow[2];
#pragma unroll
  for (int mt = 0; mt < 2; ++mt) {
    int m = base + r0 + mt * 16 + c;
    int b = m / P_, p = m - b * P_;
    arow[mt] = emb + ((size_t)(b * 2001 + 1 + p)) * D_;
    int t = tidx[m];
    trow[mt] = tourb + ((size_t)(b * T_ + t)) * D_;
  }
  float bias1[8], bias2[8];
#pragma unroll
  for (int nt = 0; nt < 8; ++nt) {
    bias1[nt] = b1[nt * 16 + c];
    bias2[nt] = b2[nt * 16 + c];
  }

  // ---- GEMM1: K=256 (cust fp32->bf16 k 0..127, tour bf16 k 128..255) ----
  floatx4 acc[2][8];
#pragma unroll
  for (int mt = 0; mt < 2; ++mt)
#pragma unroll
    for (int nt = 0; nt < 8; ++nt) acc[mt][nt] = (floatx4)0.f;

#pragma unroll
  for (int ks = 0; ks < 8; ++ks) {
    short8 a[2];
#pragma unroll
    for (int mt = 0; mt < 2; ++mt) {
      if (ks < 4) {
        const float* src = arow[mt] + ks * 32 + quad * 8;
        floatx4 x0 = *(const floatx4*)src;
        floatx4 x1 = *(const floatx4*)(src + 4);
#pragma unroll
        for (int j = 0; j < 4; ++j) {
          a[mt][j]     = (short)f2bf(x0[j]);
          a[mt][4 + j] = (short)f2bf(x1[j]);
        }
      } else {
        a[mt] = *(const short8*)(trow[mt] + (ks - 4) * 32 + quad * 8);
      }
    }
#pragma unroll
    for (int nt = 0; nt < 8; ++nt) {
      short8 bf = *(const short8*)(w1f + ((size_t)((ks * 8 + nt) * 64 + lane)) * 8);
      acc[0][nt] = __builtin_amdgcn_mfma_f32_16x16x32_bf16(a[0], bf, acc[0][nt], 0, 0, 0);
      acc[1][nt] = __builtin_amdgcn_mfma_f32_16x16x32_bf16(a[1], bf, acc[1][nt], 0, 0, 0);
    }
  }

  // epilogue 1: relu(acc + b1) -> hbuf bf16 (C layout: row = quad*4+r, col = lane&15)
#pragma unroll
  for (int mt = 0; mt < 2; ++mt)
#pragma unroll
    for (int nt = 0; nt < 8; ++nt)
#pragma unroll
      for (int r = 0; r < 4; ++r) {
        int row = r0 + mt * 16 + quad * 4 + r;
        float v = acc[mt][nt][r] + bias1[nt];
        hbuf[row * 136 + nt * 16 + c] = f2bf(v > 0.f ? v : 0.f);
      }
  __syncthreads();

  // ---- GEMM2: K=128, A-frags from hbuf ----
  floatx4 acc2[2][8];
#pragma unroll
  for (int mt = 0; mt < 2; ++mt)
#pragma unroll
    for (int nt = 0; nt < 8; ++nt) acc2[mt][nt] = (floatx4)0.f;

#pragma unroll
  for (int ks = 0; ks < 4; ++ks) {
    short8 a[2];
#pragma unroll
    for (int mt = 0; mt < 2; ++mt)
      a[mt] = *(const short8*)(&hbuf[(r0 + mt * 16 + c) * 136 + ks * 32 + quad * 8]);
#pragma unroll
    for (int nt = 0; nt < 8; ++nt) {
      short8 bf = *(const short8*)(w2f + ((size_t)((ks * 8 + nt) * 64 + lane)) * 8);
      acc2[0][nt] = __builtin_amdgcn_mfma_f32_16x16x32_bf16(a[0], bf, acc2[0][nt], 0, 0, 0);
      acc2[1][nt] = __builtin_amdgcn_mfma_f32_16x16x32_bf16(a[1], bf, acc2[1][nt], 0, 0, 0);
    }
  }

  // epilogue 2: out[b,1+p,col] = cust(fp32) + (acc2 + b2); C-layout stores:
  // lanes c=0..15 of a quad write 16 consecutive fp32 = 64B segments (efficient).
#pragma unroll
  for (int mt = 0; mt < 2; ++mt)
#pragma unroll
    for (int nt = 0; nt < 8; ++nt)
#pragma unroll
      for (int r = 0; r < 4; ++r) {
        int row = r0 + mt * 16 + quad * 4 + r;
        int m = base + row;
        int b = m / P_, p = m - b * P_;
        size_t gaddr = ((size_t)(b * 2001 + 1 + p)) * D_ + nt * 16 + c;
        out[gaddr] = emb[gaddr] + (acc2[mt][nt][r] + bias2[nt]);
      }
}

// ---- per-(b,d) sum / sumsq over the P rows of `out`. grid (16, 64) ----
__global__ __launch_bounds__(256) void k_stats(const float* __restrict__ out,
                                               float* __restrict__ ssum,
                                               float* __restrict__ ssq) {
  const int b = blockIdx.y, ps = blockIdx.x;
  const int tid = threadIdx.x;
  const int col = tid & 127, rh = tid >> 7;
  float s = 0.f, s2 = 0.f;
  const float* src = out + ((size_t)b * 2001 + 1) * D_ + col;
  for (int p = ps * 125 + rh; p < ps * 125 + 125; p += 2) {
    float v = src[(size_t)p * D_];
    s += v; s2 += v * v;
  }
  __shared__ float ls[128], ls2[128];
  if (rh == 0) { ls[col] = s; ls2[col] = s2; }
  __syncthreads();
  if (rh == 1) { ls[col] += s; ls2[col] += s2; }
  __syncthreads();
  if (rh == 0) {
    atomicAdd(&ssum[b * D_ + col], ls[col]);
    atomicAdd(&ssq[b * D_ + col], ls2[col]);
  }
}

// ---- finalize: scale = rstd*gamma, shift = beta - mean*scale ----
__global__ void k_final(const float* __restrict__ ssum, const float* __restrict__ ssq,
                        const float* __restrict__ gamma, const float* __restrict__ beta,
                        float* __restrict__ scale, float* __restrict__ shift) {
  int i = blockIdx.x * 256 + threadIdx.x;
  if (i >= B_ * D_) return;
  int col = i & 127;
  float mean = ssum[i] * (1.f / P_);
  float var = ssq[i] * (1.f / P_) - mean * mean;
  float rstd = rsqrtf(var + 1e-5f);
  float sc = rstd * gamma[col];
  scale[i] = sc;
  shift[i] = beta[col] - mean * sc;
}

// ---- in-place normalize + depot-row copy. 8004 blocks * 256 thr * 8 elems exact ----
__global__ __launch_bounds__(256) void k_out(
    const float* __restrict__ emb,
    const float* __restrict__ scale, const float* __restrict__ shift,
    float* __restrict__ out) {
  size_t i = ((size_t)blockIdx.x * 256 + threadIdx.x) * 8;
  int row = (int)(i >> 7), col = (int)(i & 127);
  int b = row / 2001, r = row - b * 2001;
  if (r == 0) {
    *(floatx4*)(out + i)     = *(const floatx4*)(emb + i);
    *(floatx4*)(out + i + 4) = *(const floatx4*)(emb + i + 4);
  } else {
    floatx4 a0 = *(const floatx4*)(out + i);
    floatx4 a1 = *(const floatx4*)(out + i + 4);
    int cc = b * D_ + col;
#pragma unroll
    for (int j = 0; j < 4; ++j) {
      a0[j] = a0[j] * scale[cc + j] + shift[cc + j];
      a1[j] = a1[j] * scale[cc + 4 + j] + shift[cc + 4 + j];
    }
    *(floatx4*)(out + i)     = a0;
    *(floatx4*)(out + i + 4) = a1;
  }
}

extern "C" void kernel_launch(void* const* d_in, const int* in_sizes, int n_in,
                              void* d_out, int out_size, void* d_ws, size_t ws_size,
                              hipStream_t stream) {
  // inputs: 0 batch_size(i32), 1 num_customers(i32), 2 tour_index(i32),
  // 3 embeddings(f32), 4 W1(f32), 5 b1(f32), 6 W2(f32), 7 b2(f32),
  // 8 gamma(f32), 9 beta(f32)
  const int*   tour_index = (const int*)d_in[2];
  const float* emb   = (const float*)d_in[3];
  const float* W1    = (const float*)d_in[4];
  const float* b1    = (const float*)d_in[5];
  const float* W2    = (const float*)d_in[6];
  const float* b2    = (const float*)d_in[7];
  const float* gamma = (const float*)d_in[8];
  const float* beta  = (const float*)d_in[9];
  float* out = (float*)d_out;
  char* ws = (char*)d_ws;

  // ws layout (~4.2 MB):
  u16*   w1f   = (u16*)(ws);                 //    65,536 B
  u16*   w2f   = (u16*)(ws + 65536);         //    32,768 B
  float* ssum  = (float*)(ws + 98304);       //    65,536 B (ssum || ssq)
  float* ssq   = ssum + B_ * D_;
  float* scale = (float*)(ws + 163840);      //    65,536 B (scale || shift)
  float* shift = scale + B_ * D_;
  u16*   tourb = (u16*)(ws + 229376);        // 3,276,800 B (bf16 tour table)
  int*   list  = (int*)(ws + 3506176);       //   512,000 B (sorted customer ids)
  int*   goff  = (int*)(ws + 4018176);       //    51,200 B
  int*   gcnt  = (int*)(ws + 4069376);       //    51,200 B

  hipLaunchKernelGGL(k_zero,   dim3(64),     dim3(256), 0, stream, ssum, 2 * B_ * D_);
  hipLaunchKernelGGL(k_prep_w, dim3(24),     dim3(256), 0, stream, W1, W2, w1f, w2f);
  hipLaunchKernelGGL(k_bin,    dim3(64),     dim3(256), 0, stream, tour_index, list, goff, gcnt);
  hipLaunchKernelGGL(k_gather, dim3(3200),   dim3(256), 0, stream, emb, list, goff, gcnt, tourb);
  hipLaunchKernelGGL(k_mlp,    dim3(1000),   dim3(256), 0, stream, tour_index, emb, tourb,
                     w1f, w2f, b1, b2, out);
  hipLaunchKernelGGL(k_stats,  dim3(16, 64), dim3(256), 0, stream, out, ssum, ssq);
  hipLaunchKernelGGL(k_final,  dim3(32),     dim3(256), 0, stream, ssum, ssq, gamma, beta,
                     scale, shift);
  hipLaunchKernelGGL(k_out,    dim3(8004),   dim3(256), 0, stream, emb, scale, shift, out);
}